// Round 1
// baseline (344.430 us; speedup 1.0000x reference)
//
#include <hip/hip_runtime.h>

constexpr int B_  = 4;
constexpr int T_  = 4096;
constexpr int C_  = 1024;
constexpr int H_  = 64;
constexpr int BT_ = B_ * T_;

typedef __attribute__((ext_vector_type(4))) float f32x4;
typedef __attribute__((ext_vector_type(8))) short bf16x8;
typedef __attribute__((ext_vector_type(8))) unsigned short u16x8;

__device__ __forceinline__ unsigned short f32_to_bf16(float f) {
    union { float f; unsigned int u; } v;
    v.f = f;
    unsigned int r = v.u + 0x7FFFu + ((v.u >> 16) & 1u);  // round-to-nearest-even
    return (unsigned short)(r >> 16);
}

// ---------------- Kernel 1: QKV projection (fp32 accumulate -> bf16 out) ----
// grid: BT_/32 blocks x 256 thr. Block handles 32 rows x all 192 outputs.
// x tile staged in LDS; W read from L2 (768 KB total, L2-resident).
__global__ __launch_bounds__(256) void proj_kernel(
    const float* __restrict__ x, const float* __restrict__ Wq,
    const float* __restrict__ Wk, const float* __restrict__ Wv,
    unsigned short* __restrict__ Qb, unsigned short* __restrict__ Kb,
    unsigned short* __restrict__ Vb)
{
    __shared__ float xs[32][64];
    const int t    = threadIdx.x;
    const int r0   = blockIdx.x * 32;
    const int h    = t & 63;     // output head-dim column
    const int rg   = t >> 6;     // wave id -> rows rg*8 .. rg*8+7
    const int srow = t >> 3;
    const int scol = (t & 7) * 8;

    float aq[8], ak[8], av[8];
#pragma unroll
    for (int i = 0; i < 8; i++) { aq[i] = 0.f; ak[i] = 0.f; av[i] = 0.f; }

    for (int cc = 0; cc < C_; cc += 64) {
        const float* xp = x + (size_t)(r0 + srow) * C_ + cc + scol;
        f32x4 v0 = *(const f32x4*)xp;
        f32x4 v1 = *(const f32x4*)(xp + 4);
        __syncthreads();
        *(f32x4*)&xs[srow][scol]     = v0;
        *(f32x4*)&xs[srow][scol + 4] = v1;
        __syncthreads();
        const float* wqp = Wq + (size_t)cc * H_ + h;
        const float* wkp = Wk + (size_t)cc * H_ + h;
        const float* wvp = Wv + (size_t)cc * H_ + h;
#pragma unroll 4
        for (int c = 0; c < 64; c++) {
            float wq = wqp[c * H_];
            float wk = wkp[c * H_];
            float wv = wvp[c * H_];
#pragma unroll
            for (int i = 0; i < 8; i++) {
                float xv = xs[rg * 8 + i][c];   // wave-uniform addr -> broadcast
                aq[i] = fmaf(xv, wq, aq[i]);
                ak[i] = fmaf(xv, wk, ak[i]);
                av[i] = fmaf(xv, wv, av[i]);
            }
        }
    }
#pragma unroll
    for (int i = 0; i < 8; i++) {
        size_t row = (size_t)r0 + rg * 8 + i;
        Qb[row * H_ + h] = f32_to_bf16(aq[i]);
        Kb[row * H_ + h] = f32_to_bf16(ak[i]);
        Vb[row * H_ + h] = f32_to_bf16(av[i]);
    }
}

// ---------------- Kernel 2: V -> V^T  ([B][T][64] -> [B][64][T]) ------------
__global__ __launch_bounds__(256) void vtrans_kernel(
    const unsigned short* __restrict__ Vb, unsigned short* __restrict__ Vt)
{
    __shared__ __align__(16) unsigned short vs[64][72];
    const int t   = threadIdx.x;
    const int r0  = blockIdx.x * 64;
    const int row = t >> 2;
    const int col = (t & 3) * 16;
    const unsigned short* src = Vb + (size_t)(r0 + row) * H_ + col;
    u16x8 a0 = *(const u16x8*)src;
    u16x8 a1 = *(const u16x8*)(src + 8);
    *(u16x8*)&vs[row][col]     = a0;
    *(u16x8*)&vs[row][col + 8] = a1;
    __syncthreads();
    const int h   = t >> 2;
    const int seg = t & 3;
    unsigned short __attribute__((aligned(16))) buf[16];
#pragma unroll
    for (int i = 0; i < 16; i++) buf[i] = vs[seg * 16 + i][h];
    const int bb = r0 / T_;
    const int tr = (r0 % T_) + seg * 16;
    unsigned short* dst = Vt + ((size_t)bb * H_ + h) * T_ + tr;
    *(u16x8*)dst       = *(const u16x8*)buf;
    *(u16x8*)(dst + 8) = *(const u16x8*)(buf + 8);
}

// ---------------- Kernel 3: causal flash attention (bf16 MFMA) --------------
// grid: B_ * (T_/16) blocks x 256 thr. Block = one 16-query tile; the 4 waves
// split the key range (chunks of 32 keys, stride 128) and merge via LDS.
// mfma_f32_16x16x32_bf16 layouts (HW-verified):
//   A-frag: A[m = lane&15][k = (lane>>4)*8 + j]
//   B-frag: B[k = (lane>>4)*8 + j][n = lane&15]
//   C/D   : col = lane&15, row = (lane>>4)*4 + reg
__global__ __launch_bounds__(256) void attn_kernel(
    const unsigned short* __restrict__ Qb, const unsigned short* __restrict__ Kb,
    const unsigned short* __restrict__ Vt, float* __restrict__ out)
{
    __shared__ __align__(16) unsigned short Pbuf[4][2][16][40]; // ping-pong, +pad
    __shared__ float Opart[4][16][64];
    __shared__ float mpart[4][16];
    __shared__ float lpart[4][16];

    const int tid  = threadIdx.x;
    const int w    = tid >> 6;
    const int lane = tid & 63;
    const int quad = lane >> 4;
    const int c    = lane & 15;
    const int b    = blockIdx.x >> 8;
    const int qt   = (T_ / 16 - 1) - (blockIdx.x & 255);  // big tiles first
    const int q0   = qt * 16;
    const size_t bT = (size_t)b * T_;

    // Q A-fragments (head dims 0-31 and 32-63), straight from global
    const unsigned short* qp = Qb + (bT + q0 + c) * H_ + quad * 8;
    const bf16x8 qA0 = *(const bf16x8*)qp;
    const bf16x8 qA1 = *(const bf16x8*)(qp + 32);

    f32x4 O0 = {0.f, 0.f, 0.f, 0.f}, O1 = O0, O2 = O0, O3 = O0;
    float m4[4], l4[4];
#pragma unroll
    for (int r = 0; r < 4; r++) { m4[r] = -1e30f; l4[r] = 0.f; }

    const float scale = 0.03125f;  // 1/sqrt(1024)
    const int qmax = q0 + 15;
    const unsigned short* vbase = Vt + ((size_t)b * H_ + c) * T_ + quad * 8;

    int pp = 0;
    for (int kb = w * 32; kb <= qmax; kb += 128, pp ^= 1) {
        // K B-fragments: keys kb..kb+15 (S0) and kb+16..kb+31 (S1)
        const unsigned short* k0 = Kb + (bT + kb + c) * H_ + quad * 8;
        const unsigned short* k1 = k0 + 16 * H_;
        bf16x8 kB00 = *(const bf16x8*)k0;
        bf16x8 kB01 = *(const bf16x8*)(k0 + 32);
        bf16x8 kB10 = *(const bf16x8*)k1;
        bf16x8 kB11 = *(const bf16x8*)(k1 + 32);

        f32x4 S0 = {0.f, 0.f, 0.f, 0.f}, S1 = S0;
        S0 = __builtin_amdgcn_mfma_f32_16x16x32_bf16(qA0, kB00, S0, 0, 0, 0);
        S0 = __builtin_amdgcn_mfma_f32_16x16x32_bf16(qA1, kB01, S0, 0, 0, 0);
        S1 = __builtin_amdgcn_mfma_f32_16x16x32_bf16(qA0, kB10, S1, 0, 0, 0);
        S1 = __builtin_amdgcn_mfma_f32_16x16x32_bf16(qA1, kB11, S1, 0, 0, 0);

        // online softmax (row r lives on the 16 lanes of this quad)
        float p0[4], p1[4];
#pragma unroll
        for (int r = 0; r < 4; r++) {
            const int qi = q0 + quad * 4 + r;
            float s0 = S0[r] * scale;
            float s1 = S1[r] * scale;
            if (kb + c > qi)      s0 = -1e30f;
            if (kb + 16 + c > qi) s1 = -1e30f;
            float mx = fmaxf(s0, s1);
            mx = fmaxf(mx, __shfl_xor(mx, 1));
            mx = fmaxf(mx, __shfl_xor(mx, 2));
            mx = fmaxf(mx, __shfl_xor(mx, 4));
            mx = fmaxf(mx, __shfl_xor(mx, 8));
            const float mn    = fmaxf(m4[r], mx);
            const float alpha = __expf(m4[r] - mn);
            const float e0 = __expf(s0 - mn);
            const float e1 = __expf(s1 - mn);
            float rs = e0 + e1;
            rs += __shfl_xor(rs, 1);
            rs += __shfl_xor(rs, 2);
            rs += __shfl_xor(rs, 4);
            rs += __shfl_xor(rs, 8);
            l4[r] = l4[r] * alpha + rs;
            m4[r] = mn;
            O0[r] *= alpha; O1[r] *= alpha; O2[r] *= alpha; O3[r] *= alpha;
            p0[r] = e0; p1[r] = e1;
        }

        // P: C-layout -> A-layout via wave-private LDS roundtrip
        unsigned short* P = &Pbuf[w][pp][0][0];
#pragma unroll
        for (int r = 0; r < 4; r++) {
            P[(quad * 4 + r) * 40 + c]      = f32_to_bf16(p0[r]);
            P[(quad * 4 + r) * 40 + c + 16] = f32_to_bf16(p1[r]);
        }
        __asm__ volatile("s_waitcnt lgkmcnt(0)" ::: "memory");
        const bf16x8 pA = *(const bf16x8*)(P + c * 40 + quad * 8);

        // PV: O[16q x 64h] += P[16x32] @ V[32 x 64], 4 h-chunks of 16
        const unsigned short* vp = vbase + kb;
        O0 = __builtin_amdgcn_mfma_f32_16x16x32_bf16(pA, *(const bf16x8*)vp,            O0, 0, 0, 0);
        O1 = __builtin_amdgcn_mfma_f32_16x16x32_bf16(pA, *(const bf16x8*)(vp + 16*T_),  O1, 0, 0, 0);
        O2 = __builtin_amdgcn_mfma_f32_16x16x32_bf16(pA, *(const bf16x8*)(vp + 32*T_),  O2, 0, 0, 0);
        O3 = __builtin_amdgcn_mfma_f32_16x16x32_bf16(pA, *(const bf16x8*)(vp + 48*T_),  O3, 0, 0, 0);
    }

    // write per-wave partials and merge (flash combine across the 4 waves)
#pragma unroll
    for (int r = 0; r < 4; r++) {
        const int row = quad * 4 + r;
        Opart[w][row][c]      = O0[r];
        Opart[w][row][c + 16] = O1[r];
        Opart[w][row][c + 32] = O2[r];
        Opart[w][row][c + 48] = O3[r];
    }
    if (c < 4) { mpart[w][quad * 4 + c] = m4[c]; lpart[w][quad * 4 + c] = l4[c]; }
    __syncthreads();

    const int h  = tid & 63;
    const int rg = tid >> 6;
#pragma unroll
    for (int i = 0; i < 4; i++) {
        const int row = rg * 4 + i;
        float M = fmaxf(fmaxf(mpart[0][row], mpart[1][row]),
                        fmaxf(mpart[2][row], mpart[3][row]));
        float L = 0.f, val = 0.f;
#pragma unroll
        for (int w2 = 0; w2 < 4; w2++) {
            const float e = __expf(mpart[w2][row] - M);   // empty wave: e -> 0
            L   = fmaf(lpart[w2][row], e, L);
            val = fmaf(Opart[w2][row][h], e, val);
        }
        out[(bT + q0 + row) * H_ + h] = val / L;
    }
}

extern "C" void kernel_launch(void* const* d_in, const int* in_sizes, int n_in,
                              void* d_out, int out_size, void* d_ws, size_t ws_size,
                              hipStream_t stream) {
    const float* x  = (const float*)d_in[0];
    const float* Wq = (const float*)d_in[1];
    const float* Wk = (const float*)d_in[2];
    const float* Wv = (const float*)d_in[3];
    float* out = (float*)d_out;

    // workspace: Qb | Kb | Vb | Vt, each B*T*64 bf16 = 2 MiB (8 MiB total)
    unsigned short* Qb = (unsigned short*)d_ws;
    unsigned short* Kb = Qb + (size_t)BT_ * H_;
    unsigned short* Vb = Kb + (size_t)BT_ * H_;
    unsigned short* Vt = Vb + (size_t)BT_ * H_;

    proj_kernel<<<BT_ / 32, 256, 0, stream>>>(x, Wq, Wk, Wv, Qb, Kb, Vb);
    vtrans_kernel<<<BT_ / 64, 256, 0, stream>>>(Vb, Vt);
    attn_kernel<<<B_ * (T_ / 16), 256, 0, stream>>>(Qb, Kb, Vt, out);
}

// Round 3
// 243.322 us; speedup vs baseline: 1.4155x; 1.4155x over previous
//
#include <hip/hip_runtime.h>

constexpr int B_  = 4;
constexpr int T_  = 4096;
constexpr int C_  = 1024;
constexpr int H_  = 64;
constexpr int BT_ = B_ * T_;

typedef __attribute__((ext_vector_type(4))) float f32x4;
typedef __attribute__((ext_vector_type(8))) short bf16x8;
typedef __attribute__((ext_vector_type(8))) unsigned short u16x8;

__device__ __forceinline__ unsigned short f32_to_bf16(float f) {
    union { float f; unsigned int u; } v;
    v.f = f;
    unsigned int r = v.u + 0x7FFFu + ((v.u >> 16) & 1u);  // round-to-nearest-even
    return (unsigned short)(r >> 16);
}

// ---------------- Kernel 0: W transpose+cast ->  Wt bf16 [192 n][1024 k] ----
// n 0-63 = Wq cols, 64-127 = Wk, 128-191 = Wv. Makes MFMA B-fragments direct
// contiguous 16B global loads (L2-resident, 384 KB).
__global__ __launch_bounds__(256) void wconv_kernel(
    const float* __restrict__ Wq, const float* __restrict__ Wk,
    const float* __restrict__ Wv, unsigned short* __restrict__ Wt)
{
    __shared__ float ls[64][65];
    const int blk = blockIdx.x;            // 48 blocks: 3 matrices x 16 k-tiles
    const int m   = blk >> 4;
    const int k0  = (blk & 15) * 64;
    const float* W = (m == 0) ? Wq : (m == 1) ? Wk : Wv;
    const int t = threadIdx.x;
#pragma unroll
    for (int i = 0; i < 16; i++) {
        const int e = i * 256 + t, row = e >> 6, col = e & 63;
        ls[col][row] = W[(size_t)(k0 + row) * H_ + col];   // coalesced read
    }
    __syncthreads();
#pragma unroll
    for (int i = 0; i < 16; i++) {
        const int e = i * 256 + t, col = e >> 6, row = e & 63;
        Wt[(size_t)(m * H_ + col) * C_ + k0 + row] = f32_to_bf16(ls[col][row]);
    }
}

// ---------------- Kernel 1: QKV projection via bf16 MFMA --------------------
// grid: 256 blocks x 256 thr. Block = 64 rows x all 192 outputs.
// Wave w: m-half (w&1)*32 (2 m-tiles), n-half (w>>1)*96 (6 n-tiles)
//   -> 12 f32x4 accumulators; 12 MFMAs per 32-k step.
// x staged fp32->bf16 in LDS (stride 72 shorts: 2-way bank aliasing = free);
// B-frags read straight from L2-resident Wt.
__global__ __launch_bounds__(256) void proj_kernel(
    const float* __restrict__ x, const unsigned short* __restrict__ Wt,
    unsigned short* __restrict__ Qb, unsigned short* __restrict__ Kb,
    unsigned short* __restrict__ Vb)
{
    __shared__ __align__(16) unsigned short xs[64][72];
    const int t    = threadIdx.x;
    const int r0   = blockIdx.x * 64;
    const int w    = t >> 6;
    const int lane = t & 63;
    const int quad = lane >> 4;
    const int c    = lane & 15;
    const int mh   = (w & 1) * 32;
    const int nh   = (w >> 1) * 96;
    const int srow = t >> 2;
    const int koff = (t & 3) * 16;

    f32x4 acc[2][6];
#pragma unroll
    for (int mi = 0; mi < 2; mi++)
#pragma unroll
        for (int j = 0; j < 6; j++) acc[mi][j] = {0.f, 0.f, 0.f, 0.f};

    for (int kk = 0; kk < C_; kk += 64) {
        // stage 64 rows x 64 k, fp32 -> bf16
        const float* xp = x + (size_t)(r0 + srow) * C_ + kk + koff;
        f32x4 v0 = *(const f32x4*)xp;
        f32x4 v1 = *(const f32x4*)(xp + 4);
        f32x4 v2 = *(const f32x4*)(xp + 8);
        f32x4 v3 = *(const f32x4*)(xp + 12);
        __syncthreads();
        u16x8 p0, p1;
#pragma unroll
        for (int i = 0; i < 4; i++) {
            p0[i] = f32_to_bf16(v0[i]); p0[4 + i] = f32_to_bf16(v1[i]);
            p1[i] = f32_to_bf16(v2[i]); p1[4 + i] = f32_to_bf16(v3[i]);
        }
        *(u16x8*)&xs[srow][koff]     = p0;
        *(u16x8*)&xs[srow][koff + 8] = p1;
        __syncthreads();

#pragma unroll
        for (int ks = 0; ks < 64; ks += 32) {
            const bf16x8 a0 = *(const bf16x8*)&xs[mh + c][ks + quad * 8];
            const bf16x8 a1 = *(const bf16x8*)&xs[mh + 16 + c][ks + quad * 8];
            const unsigned short* bp =
                Wt + (size_t)(nh + c) * C_ + kk + ks + quad * 8;
#pragma unroll
            for (int j = 0; j < 6; j++) {
                const bf16x8 bj = *(const bf16x8*)(bp + (size_t)j * 16 * C_);
                acc[0][j] = __builtin_amdgcn_mfma_f32_16x16x32_bf16(a0, bj, acc[0][j], 0, 0, 0);
                acc[1][j] = __builtin_amdgcn_mfma_f32_16x16x32_bf16(a1, bj, acc[1][j], 0, 0, 0);
            }
        }
    }

    // epilogue: D layout col = lane&15, row = quad*4 + reg
#pragma unroll
    for (int mi = 0; mi < 2; mi++) {
#pragma unroll
        for (int j = 0; j < 6; j++) {
            const int n = nh + j * 16 + c;          // wave-uniform branch below
            unsigned short* dst = (n < 64) ? (Qb + n)
                                : (n < 128) ? (Kb + n - 64)
                                            : (Vb + n - 128);
#pragma unroll
            for (int r = 0; r < 4; r++) {
                const size_t row = (size_t)r0 + mh + mi * 16 + quad * 4 + r;
                dst[row * H_] = f32_to_bf16(acc[mi][j][r]);
            }
        }
    }
}

// ---------------- Kernel 2: V -> V^T  ([B][T][64] -> [B][64][T]) ------------
__global__ __launch_bounds__(256) void vtrans_kernel(
    const unsigned short* __restrict__ Vb, unsigned short* __restrict__ Vt)
{
    __shared__ __align__(16) unsigned short vs[64][72];
    const int t   = threadIdx.x;
    const int r0  = blockIdx.x * 64;
    const int row = t >> 2;
    const int col = (t & 3) * 16;
    const unsigned short* src = Vb + (size_t)(r0 + row) * H_ + col;
    u16x8 a0 = *(const u16x8*)src;
    u16x8 a1 = *(const u16x8*)(src + 8);
    *(u16x8*)&vs[row][col]     = a0;
    *(u16x8*)&vs[row][col + 8] = a1;
    __syncthreads();
    const int h   = t >> 2;
    const int seg = t & 3;
    unsigned short __attribute__((aligned(16))) buf[16];
#pragma unroll
    for (int i = 0; i < 16; i++) buf[i] = vs[seg * 16 + i][h];
    const int bb = r0 / T_;
    const int tr = (r0 % T_) + seg * 16;
    unsigned short* dst = Vt + ((size_t)bb * H_ + h) * T_ + tr;
    *(u16x8*)dst       = *(const u16x8*)buf;
    *(u16x8*)(dst + 8) = *(const u16x8*)(buf + 8);
}

// ---------------- Kernel 3: causal flash attention (bf16 MFMA) --------------
// (unchanged from round 1 — verified correct)
__global__ __launch_bounds__(256) void attn_kernel(
    const unsigned short* __restrict__ Qb, const unsigned short* __restrict__ Kb,
    const unsigned short* __restrict__ Vt, float* __restrict__ out)
{
    __shared__ __align__(16) unsigned short Pbuf[4][2][16][40]; // ping-pong, +pad
    __shared__ float Opart[4][16][64];
    __shared__ float mpart[4][16];
    __shared__ float lpart[4][16];

    const int tid  = threadIdx.x;
    const int w    = tid >> 6;
    const int lane = tid & 63;
    const int quad = lane >> 4;
    const int c    = lane & 15;
    const int b    = blockIdx.x >> 8;
    const int qt   = (T_ / 16 - 1) - (blockIdx.x & 255);  // big tiles first
    const int q0   = qt * 16;
    const size_t bT = (size_t)b * T_;

    const unsigned short* qp = Qb + (bT + q0 + c) * H_ + quad * 8;
    const bf16x8 qA0 = *(const bf16x8*)qp;
    const bf16x8 qA1 = *(const bf16x8*)(qp + 32);

    f32x4 O0 = {0.f, 0.f, 0.f, 0.f}, O1 = O0, O2 = O0, O3 = O0;
    float m4[4], l4[4];
#pragma unroll
    for (int r = 0; r < 4; r++) { m4[r] = -1e30f; l4[r] = 0.f; }

    const float scale = 0.03125f;  // 1/sqrt(1024)
    const int qmax = q0 + 15;
    const unsigned short* vbase = Vt + ((size_t)b * H_ + c) * T_ + quad * 8;

    int pp = 0;
    for (int kb = w * 32; kb <= qmax; kb += 128, pp ^= 1) {
        const unsigned short* k0 = Kb + (bT + kb + c) * H_ + quad * 8;
        const unsigned short* k1 = k0 + 16 * H_;
        bf16x8 kB00 = *(const bf16x8*)k0;
        bf16x8 kB01 = *(const bf16x8*)(k0 + 32);
        bf16x8 kB10 = *(const bf16x8*)k1;
        bf16x8 kB11 = *(const bf16x8*)(k1 + 32);

        f32x4 S0 = {0.f, 0.f, 0.f, 0.f}, S1 = S0;
        S0 = __builtin_amdgcn_mfma_f32_16x16x32_bf16(qA0, kB00, S0, 0, 0, 0);
        S0 = __builtin_amdgcn_mfma_f32_16x16x32_bf16(qA1, kB01, S0, 0, 0, 0);
        S1 = __builtin_amdgcn_mfma_f32_16x16x32_bf16(qA0, kB10, S1, 0, 0, 0);
        S1 = __builtin_amdgcn_mfma_f32_16x16x32_bf16(qA1, kB11, S1, 0, 0, 0);

        float p0[4], p1[4];
#pragma unroll
        for (int r = 0; r < 4; r++) {
            const int qi = q0 + quad * 4 + r;
            float s0 = S0[r] * scale;
            float s1 = S1[r] * scale;
            if (kb + c > qi)      s0 = -1e30f;
            if (kb + 16 + c > qi) s1 = -1e30f;
            float mx = fmaxf(s0, s1);
            mx = fmaxf(mx, __shfl_xor(mx, 1));
            mx = fmaxf(mx, __shfl_xor(mx, 2));
            mx = fmaxf(mx, __shfl_xor(mx, 4));
            mx = fmaxf(mx, __shfl_xor(mx, 8));
            const float mn    = fmaxf(m4[r], mx);
            const float alpha = __expf(m4[r] - mn);
            const float e0 = __expf(s0 - mn);
            const float e1 = __expf(s1 - mn);
            float rs = e0 + e1;
            rs += __shfl_xor(rs, 1);
            rs += __shfl_xor(rs, 2);
            rs += __shfl_xor(rs, 4);
            rs += __shfl_xor(rs, 8);
            l4[r] = l4[r] * alpha + rs;
            m4[r] = mn;
            O0[r] *= alpha; O1[r] *= alpha; O2[r] *= alpha; O3[r] *= alpha;
            p0[r] = e0; p1[r] = e1;
        }

        unsigned short* P = &Pbuf[w][pp][0][0];
#pragma unroll
        for (int r = 0; r < 4; r++) {
            P[(quad * 4 + r) * 40 + c]      = f32_to_bf16(p0[r]);
            P[(quad * 4 + r) * 40 + c + 16] = f32_to_bf16(p1[r]);
        }
        __asm__ volatile("s_waitcnt lgkmcnt(0)" ::: "memory");
        const bf16x8 pA = *(const bf16x8*)(P + c * 40 + quad * 8);

        const unsigned short* vp = vbase + kb;
        O0 = __builtin_amdgcn_mfma_f32_16x16x32_bf16(pA, *(const bf16x8*)vp,            O0, 0, 0, 0);
        O1 = __builtin_amdgcn_mfma_f32_16x16x32_bf16(pA, *(const bf16x8*)(vp + 16*T_),  O1, 0, 0, 0);
        O2 = __builtin_amdgcn_mfma_f32_16x16x32_bf16(pA, *(const bf16x8*)(vp + 32*T_),  O2, 0, 0, 0);
        O3 = __builtin_amdgcn_mfma_f32_16x16x32_bf16(pA, *(const bf16x8*)(vp + 48*T_),  O3, 0, 0, 0);
    }

#pragma unroll
    for (int r = 0; r < 4; r++) {
        const int row = quad * 4 + r;
        Opart[w][row][c]      = O0[r];
        Opart[w][row][c + 16] = O1[r];
        Opart[w][row][c + 32] = O2[r];
        Opart[w][row][c + 48] = O3[r];
    }
    if (c < 4) { mpart[w][quad * 4 + c] = m4[c]; lpart[w][quad * 4 + c] = l4[c]; }
    __syncthreads();

    const int h  = tid & 63;
    const int rg = tid >> 6;
#pragma unroll
    for (int i = 0; i < 4; i++) {
        const int row = rg * 4 + i;
        float M = fmaxf(fmaxf(mpart[0][row], mpart[1][row]),
                        fmaxf(mpart[2][row], mpart[3][row]));
        float L = 0.f, val = 0.f;
#pragma unroll
        for (int w2 = 0; w2 < 4; w2++) {
            const float e = __expf(mpart[w2][row] - M);
            L   = fmaf(lpart[w2][row], e, L);
            val = fmaf(Opart[w2][row][h], e, val);
        }
        out[(bT + q0 + row) * H_ + h] = val / L;
    }
}

extern "C" void kernel_launch(void* const* d_in, const int* in_sizes, int n_in,
                              void* d_out, int out_size, void* d_ws, size_t ws_size,
                              hipStream_t stream) {
    const float* x  = (const float*)d_in[0];
    const float* Wq = (const float*)d_in[1];
    const float* Wk = (const float*)d_in[2];
    const float* Wv = (const float*)d_in[3];
    float* out = (float*)d_out;

    // workspace: Qb | Kb | Vb | Vt (each B*T*64 bf16 = 2 MiB) | Wt (384 KiB)
    unsigned short* Qb = (unsigned short*)d_ws;
    unsigned short* Kb = Qb + (size_t)BT_ * H_;
    unsigned short* Vb = Kb + (size_t)BT_ * H_;
    unsigned short* Vt = Vb + (size_t)BT_ * H_;
    unsigned short* Wt = Vt + (size_t)BT_ * H_;

    wconv_kernel<<<48, 256, 0, stream>>>(Wq, Wk, Wv, Wt);
    proj_kernel<<<BT_ / 64, 256, 0, stream>>>(x, Wt, Qb, Kb, Vb);
    vtrans_kernel<<<BT_ / 64, 256, 0, stream>>>(Vb, Vt);
    attn_kernel<<<B_ * (T_ / 16), 256, 0, stream>>>(Qb, Kb, Vt, out);
}

// Round 4
// 232.340 us; speedup vs baseline: 1.4824x; 1.0473x over previous
//
#include <hip/hip_runtime.h>

constexpr int B_  = 4;
constexpr int T_  = 4096;
constexpr int C_  = 1024;
constexpr int H_  = 64;
constexpr int BT_ = B_ * T_;
constexpr int SEG = 2048;   // attention key-segment per block (flash-decoding split)

typedef __attribute__((ext_vector_type(4))) float f32x4;
typedef __attribute__((ext_vector_type(8))) short bf16x8;
typedef __attribute__((ext_vector_type(8))) unsigned short u16x8;

__device__ __forceinline__ unsigned short f32_to_bf16(float f) {
    union { float f; unsigned int u; } v;
    v.f = f;
    unsigned int r = v.u + 0x7FFFu + ((v.u >> 16) & 1u);  // round-to-nearest-even
    return (unsigned short)(r >> 16);
}
__device__ __forceinline__ float bf16_to_f32(unsigned short us) {
    union { unsigned int u; float f; } v;
    v.u = (unsigned int)us << 16;
    return v.f;
}

// ---------------- Kernel 0: W transpose+cast ->  Wt bf16 [192 n][1024 k] ----
__global__ __launch_bounds__(256) void wconv_kernel(
    const float* __restrict__ Wq, const float* __restrict__ Wk,
    const float* __restrict__ Wv, unsigned short* __restrict__ Wt)
{
    __shared__ float ls[64][65];
    const int blk = blockIdx.x;            // 48 blocks: 3 matrices x 16 k-tiles
    const int m   = blk >> 4;
    const int k0  = (blk & 15) * 64;
    const float* W = (m == 0) ? Wq : (m == 1) ? Wk : Wv;
    const int t = threadIdx.x;
#pragma unroll
    for (int i = 0; i < 16; i++) {
        const int e = i * 256 + t, row = e >> 6, col = e & 63;
        ls[col][row] = W[(size_t)(k0 + row) * H_ + col];   // coalesced read
    }
    __syncthreads();
#pragma unroll
    for (int i = 0; i < 16; i++) {
        const int e = i * 256 + t, col = e >> 6, row = e & 63;
        Wt[(size_t)(m * H_ + col) * C_ + k0 + row] = f32_to_bf16(ls[col][row]);
    }
}

// ---------------- Kernel 1: QKV projection via bf16 MFMA --------------------
// 512 blocks (2/CU) x 256 thr. Block = 32 rows x all 192 outputs.
// Wave w: n-quarter w*48 (3 n-tiles) x both 16-row m-tiles -> 6 accumulators.
// Next x-tile prefetched into registers before the MFMA loop (hide HBM lat).
__global__ __launch_bounds__(256) void proj_kernel(
    const float* __restrict__ x, const unsigned short* __restrict__ Wt,
    unsigned short* __restrict__ Qb, unsigned short* __restrict__ Kb,
    unsigned short* __restrict__ Vb)
{
    __shared__ __align__(16) unsigned short xs[32][72];
    const int t    = threadIdx.x;
    const int r0   = blockIdx.x * 32;
    const int w    = t >> 6;
    const int lane = t & 63;
    const int quad = lane >> 4;
    const int c    = lane & 15;
    const int nh   = w * 48;
    const int srow = t >> 3;        // 32 rows, 8 threads/row
    const int koff = (t & 7) * 8;   // 8 floats each

    f32x4 acc[2][3];
#pragma unroll
    for (int mi = 0; mi < 2; mi++)
#pragma unroll
        for (int j = 0; j < 3; j++) acc[mi][j] = {0.f, 0.f, 0.f, 0.f};

    const float* xp = x + (size_t)(r0 + srow) * C_ + koff;
    f32x4 v0 = *(const f32x4*)xp;          // prefetch tile kk=0
    f32x4 v1 = *(const f32x4*)(xp + 4);

    for (int kk = 0; kk < C_; kk += 64) {
        u16x8 p;
#pragma unroll
        for (int i = 0; i < 4; i++) { p[i] = f32_to_bf16(v0[i]); p[4 + i] = f32_to_bf16(v1[i]); }
        __syncthreads();
        *(u16x8*)&xs[srow][koff] = p;
        __syncthreads();
        if (kk + 64 < C_) {                 // prefetch next tile (overlaps MFMAs)
            v0 = *(const f32x4*)(xp + kk + 64);
            v1 = *(const f32x4*)(xp + kk + 68);
        }
#pragma unroll
        for (int ks = 0; ks < 64; ks += 32) {
            const bf16x8 a0 = *(const bf16x8*)&xs[c][ks + quad * 8];
            const bf16x8 a1 = *(const bf16x8*)&xs[16 + c][ks + quad * 8];
            const unsigned short* bp =
                Wt + (size_t)(nh + c) * C_ + kk + ks + quad * 8;
#pragma unroll
            for (int j = 0; j < 3; j++) {
                const bf16x8 bj = *(const bf16x8*)(bp + (size_t)j * 16 * C_);
                acc[0][j] = __builtin_amdgcn_mfma_f32_16x16x32_bf16(a0, bj, acc[0][j], 0, 0, 0);
                acc[1][j] = __builtin_amdgcn_mfma_f32_16x16x32_bf16(a1, bj, acc[1][j], 0, 0, 0);
            }
        }
    }

#pragma unroll
    for (int mi = 0; mi < 2; mi++) {
#pragma unroll
        for (int j = 0; j < 3; j++) {
            const int n = nh + j * 16 + c;   // 16-aligned range: branch is wave-uniform
            unsigned short* dst = (n < 64) ? (Qb + n)
                                : (n < 128) ? (Kb + n - 64)
                                            : (Vb + n - 128);
#pragma unroll
            for (int r = 0; r < 4; r++) {
                const size_t row = (size_t)r0 + mi * 16 + quad * 4 + r;
                dst[row * H_] = f32_to_bf16(acc[mi][j][r]);
            }
        }
    }
}

// ---------------- Kernel 2: V -> V^T  ([B][T][64] -> [B][64][T]) ------------
__global__ __launch_bounds__(256) void vtrans_kernel(
    const unsigned short* __restrict__ Vb, unsigned short* __restrict__ Vt)
{
    __shared__ __align__(16) unsigned short vs[64][72];
    const int t   = threadIdx.x;
    const int r0  = blockIdx.x * 64;
    const int row = t >> 2;
    const int col = (t & 3) * 16;
    const unsigned short* src = Vb + (size_t)(r0 + row) * H_ + col;
    u16x8 a0 = *(const u16x8*)src;
    u16x8 a1 = *(const u16x8*)(src + 8);
    *(u16x8*)&vs[row][col]     = a0;
    *(u16x8*)&vs[row][col + 8] = a1;
    __syncthreads();
    const int h   = t >> 2;
    const int seg = t & 3;
    unsigned short __attribute__((aligned(16))) buf[16];
#pragma unroll
    for (int i = 0; i < 16; i++) buf[i] = vs[seg * 16 + i][h];
    const int bb = r0 / T_;
    const int tr = (r0 % T_) + seg * 16;
    unsigned short* dst = Vt + ((size_t)bb * H_ + h) * T_ + tr;
    *(u16x8*)dst       = *(const u16x8*)buf;
    *(u16x8*)(dst + 8) = *(const u16x8*)(buf + 8);
}

// ---------------- Kernel 3: causal flash attention, key-segmented -----------
// 2048 blocks: idx = (b<<9) | (qtcode<<1) | seg, qt = 255-qtcode (big first).
// Block covers keys [seg*SEG, seg*SEG+SEG) for one 16-query tile; 4 waves
// split the segment's 32-key chunks mod 4. Writes UNNORMALIZED partial
// (O bf16, m/l f32) per (b,qt,seg); merge_kernel combines & normalizes.
__global__ __launch_bounds__(256) void attn_kernel(
    const unsigned short* __restrict__ Qb, const unsigned short* __restrict__ Kb,
    const unsigned short* __restrict__ Vt, unsigned short* __restrict__ Opg,
    float* __restrict__ mlg)
{
    __shared__ __align__(16) unsigned short Pbuf[4][16][40];
    __shared__ float Osh[4][16][64];
    __shared__ float msh[4][16];
    __shared__ float lsh[4][16];

    const int tid  = threadIdx.x;
    const int w    = tid >> 6;
    const int lane = tid & 63;
    const int quad = lane >> 4;
    const int c    = lane & 15;
    const int idx  = blockIdx.x;
    const int b    = idx >> 9;
    const int qt   = 255 - ((idx >> 1) & 255);
    const int seg  = idx & 1;
    if (seg == 1 && qt < 128) return;      // segment beyond causal horizon
    const int q0    = qt * 16;
    const int qmax  = q0 + 15;
    const int k0seg = seg * SEG;
    const int kend  = (qmax < k0seg + SEG - 1) ? qmax : (k0seg + SEG - 1);
    const size_t bT = (size_t)b * T_;

    const unsigned short* qp = Qb + (bT + q0 + c) * H_ + quad * 8;
    const bf16x8 qA0 = *(const bf16x8*)qp;
    const bf16x8 qA1 = *(const bf16x8*)(qp + 32);

    f32x4 O0 = {0.f, 0.f, 0.f, 0.f}, O1 = O0, O2 = O0, O3 = O0;
    float m4[4], ls4[4];
#pragma unroll
    for (int r = 0; r < 4; r++) { m4[r] = -1e30f; ls4[r] = 0.f; }

    const float scale = 0.03125f;  // 1/sqrt(1024)
    const unsigned short* vbase = Vt + ((size_t)b * H_ + c) * T_ + quad * 8;

    for (int kb = k0seg + w * 32; kb <= kend; kb += 128) {
        const unsigned short* k0p = Kb + (bT + kb + c) * H_ + quad * 8;
        const unsigned short* k1p = k0p + 16 * H_;
        bf16x8 kB00 = *(const bf16x8*)k0p;
        bf16x8 kB01 = *(const bf16x8*)(k0p + 32);
        bf16x8 kB10 = *(const bf16x8*)k1p;
        bf16x8 kB11 = *(const bf16x8*)(k1p + 32);

        f32x4 S0 = {0.f, 0.f, 0.f, 0.f}, S1 = S0;
        S0 = __builtin_amdgcn_mfma_f32_16x16x32_bf16(qA0, kB00, S0, 0, 0, 0);
        S0 = __builtin_amdgcn_mfma_f32_16x16x32_bf16(qA1, kB01, S0, 0, 0, 0);
        S1 = __builtin_amdgcn_mfma_f32_16x16x32_bf16(qA0, kB10, S1, 0, 0, 0);
        S1 = __builtin_amdgcn_mfma_f32_16x16x32_bf16(qA1, kB11, S1, 0, 0, 0);

        const bool domask = (kb + 31 > q0);  // wave-uniform; interior chunks skip
        float p0[4], p1[4];
#pragma unroll
        for (int r = 0; r < 4; r++) {
            const int qi = q0 + quad * 4 + r;
            float s0 = S0[r] * scale;
            float s1 = S1[r] * scale;
            if (domask) {
                if (kb + c > qi)      s0 = -1e30f;
                if (kb + 16 + c > qi) s1 = -1e30f;
            }
            float mx = fmaxf(s0, s1);
            mx = fmaxf(mx, __shfl_xor(mx, 1));
            mx = fmaxf(mx, __shfl_xor(mx, 2));
            mx = fmaxf(mx, __shfl_xor(mx, 4));
            mx = fmaxf(mx, __shfl_xor(mx, 8));
            const float mn    = fmaxf(m4[r], mx);
            const float alpha = __expf(m4[r] - mn);
            const float e0 = __expf(s0 - mn);
            const float e1 = __expf(s1 - mn);
            ls4[r] = ls4[r] * alpha + (e0 + e1);   // deferred cross-lane sum
            m4[r] = mn;
            O0[r] *= alpha; O1[r] *= alpha; O2[r] *= alpha; O3[r] *= alpha;
            p0[r] = e0; p1[r] = e1;
        }

        // P: C-layout -> A-layout via wave-private LDS (same-wave DS ops are
        // in-order; compiler inserts the lgkmcnt before pA's MFMA use)
        unsigned short* P = &Pbuf[w][0][0];
#pragma unroll
        for (int r = 0; r < 4; r++) {
            P[(quad * 4 + r) * 40 + c]      = f32_to_bf16(p0[r]);
            P[(quad * 4 + r) * 40 + c + 16] = f32_to_bf16(p1[r]);
        }
        const bf16x8 pA = *(const bf16x8*)(P + c * 40 + quad * 8);

        const unsigned short* vp = vbase + kb;
        O0 = __builtin_amdgcn_mfma_f32_16x16x32_bf16(pA, *(const bf16x8*)vp,            O0, 0, 0, 0);
        O1 = __builtin_amdgcn_mfma_f32_16x16x32_bf16(pA, *(const bf16x8*)(vp + 16*T_),  O1, 0, 0, 0);
        O2 = __builtin_amdgcn_mfma_f32_16x16x32_bf16(pA, *(const bf16x8*)(vp + 32*T_),  O2, 0, 0, 0);
        O3 = __builtin_amdgcn_mfma_f32_16x16x32_bf16(pA, *(const bf16x8*)(vp + 48*T_),  O3, 0, 0, 0);
    }

    // cross-lane l reduction (once, not per chunk)
    float l4[4];
#pragma unroll
    for (int r = 0; r < 4; r++) {
        float l = ls4[r];
        l += __shfl_xor(l, 1);
        l += __shfl_xor(l, 2);
        l += __shfl_xor(l, 4);
        l += __shfl_xor(l, 8);
        l4[r] = l;
    }

#pragma unroll
    for (int r = 0; r < 4; r++) {
        const int row = quad * 4 + r;
        Osh[w][row][c]      = O0[r];
        Osh[w][row][c + 16] = O1[r];
        Osh[w][row][c + 32] = O2[r];
        Osh[w][row][c + 48] = O3[r];
    }
    if (c < 4) { msh[w][quad * 4 + c] = m4[c]; lsh[w][quad * 4 + c] = l4[c]; }
    __syncthreads();

    // combine the 4 waves -> one partial for this (b,qt,seg)
    const int h  = tid & 63;
    const int rg = tid >> 6;
    const size_t pidx = ((size_t)(b * 256 + qt)) * 2 + seg;
#pragma unroll
    for (int i = 0; i < 4; i++) {
        const int row = rg * 4 + i;
        float M = fmaxf(fmaxf(msh[0][row], msh[1][row]),
                        fmaxf(msh[2][row], msh[3][row]));
        float L = 0.f, val = 0.f;
#pragma unroll
        for (int w2 = 0; w2 < 4; w2++) {
            const float e = __expf(msh[w2][row] - M);   // idle wave -> e = 0
            L   = fmaf(lsh[w2][row], e, L);
            val = fmaf(Osh[w2][row][h], e, val);
        }
        Opg[pidx * 1024 + row * 64 + h] = f32_to_bf16(val);
        if (h == 0) { mlg[pidx * 32 + row] = M; mlg[pidx * 32 + 16 + row] = L; }
    }
}

// ---------------- Kernel 4: merge segments + normalize ----------------------
__global__ __launch_bounds__(256) void merge_kernel(
    const unsigned short* __restrict__ Opg, const float* __restrict__ mlg,
    float* __restrict__ out)
{
    const int idx = blockIdx.x;          // 1024 = b*256 + qt
    const int b   = idx >> 8;
    const int qt  = idx & 255;
    const int q0  = qt * 16;
    const int t   = threadIdx.x;
    const int h   = t & 63;
    const int rg  = t >> 6;
    const size_t p0i = (size_t)idx * 2;
    const bool   two = (qt >= 128);
#pragma unroll
    for (int i = 0; i < 4; i++) {
        const int row = rg * 4 + i;
        const float m0 = mlg[p0i * 32 + row];
        const float l0 = mlg[p0i * 32 + 16 + row];
        const float v0 = bf16_to_f32(Opg[p0i * 1024 + row * 64 + h]);
        float val, L;
        if (two) {
            const float m1 = mlg[(p0i + 1) * 32 + row];
            const float l1 = mlg[(p0i + 1) * 32 + 16 + row];
            const float v1 = bf16_to_f32(Opg[(p0i + 1) * 1024 + row * 64 + h]);
            const float M  = fmaxf(m0, m1);
            const float e0 = __expf(m0 - M);
            const float e1 = __expf(m1 - M);
            val = v0 * e0 + v1 * e1;
            L   = l0 * e0 + l1 * e1;
        } else {
            val = v0; L = l0;
        }
        out[((size_t)b * T_ + q0 + row) * H_ + h] = val / L;
    }
}

extern "C" void kernel_launch(void* const* d_in, const int* in_sizes, int n_in,
                              void* d_out, int out_size, void* d_ws, size_t ws_size,
                              hipStream_t stream) {
    const float* x  = (const float*)d_in[0];
    const float* Wq = (const float*)d_in[1];
    const float* Wk = (const float*)d_in[2];
    const float* Wv = (const float*)d_in[3];
    float* out = (float*)d_out;

    // ws: Qb|Kb|Vb|Vt (2 MiB each) | Wt 384 KiB | Opg 4 MiB | mlg 256 KiB
    unsigned short* Qb = (unsigned short*)d_ws;
    unsigned short* Kb = Qb + (size_t)BT_ * H_;
    unsigned short* Vb = Kb + (size_t)BT_ * H_;
    unsigned short* Vt = Vb + (size_t)BT_ * H_;
    unsigned short* Wt = Vt + (size_t)BT_ * H_;
    unsigned short* Opg = Wt + (size_t)192 * C_;
    float*          mlg = (float*)(Opg + (size_t)2048 * 1024);

    wconv_kernel<<<48, 256, 0, stream>>>(Wq, Wk, Wv, Wt);
    proj_kernel<<<BT_ / 32, 256, 0, stream>>>(x, Wt, Qb, Kb, Vb);
    vtrans_kernel<<<BT_ / 64, 256, 0, stream>>>(Vb, Vt);
    attn_kernel<<<2048, 256, 0, stream>>>(Qb, Kb, Vt, Opg, mlg);
    merge_kernel<<<1024, 256, 0, stream>>>(Opg, mlg, out);
}

// Round 7
// 182.488 us; speedup vs baseline: 1.8874x; 1.2732x over previous
//
#include <hip/hip_runtime.h>

constexpr int B_  = 4;
constexpr int T_  = 4096;
constexpr int C_  = 1024;
constexpr int H_  = 64;
constexpr int BT_ = B_ * T_;
constexpr int NUNIT_ = 1152;   // 512-key work units per batch: sum_qt (qt/32+1)

typedef __attribute__((ext_vector_type(4))) float f32x4;
typedef __attribute__((ext_vector_type(8))) short bf16x8;
typedef __attribute__((ext_vector_type(8))) unsigned short u16x8;
typedef __attribute__((ext_vector_type(4))) unsigned short u16x4;

__device__ __forceinline__ unsigned short f32_to_bf16(float f) {
    union { float f; unsigned int u; } v;
    v.f = f;
    unsigned int r = v.u + 0x7FFFu + ((v.u >> 16) & 1u);  // RNE
    return (unsigned short)(r >> 16);
}
__device__ __forceinline__ float bf16_to_f32(unsigned short us) {
    union { unsigned int u; float f; } v;
    v.u = (unsigned int)us << 16;
    return v.f;
}
// 2^x via v_exp_f32 (hardware transcendental); __exp2f does not exist in HIP.
__device__ __forceinline__ float exp2_hw(float x) {
    return __builtin_amdgcn_exp2f(x);
}

// ---- Kernel 0: W -> fragment-order Wt --------------------------------------
// Wt[(ntile*32 + kstep)*512 + lane*8 + j] = B-frag for MFMA(n-tile, 32k-step):
// lane(q,c): element j = W[n = ntile*16+c][k = kstep*32 + q*8 + j] (bf16).
__global__ __launch_bounds__(256) void wconv_kernel(
    const float* __restrict__ Wq, const float* __restrict__ Wk,
    const float* __restrict__ Wv, unsigned short* __restrict__ Wt)
{
    const int tid  = threadIdx.x;
    const int wid  = blockIdx.x * 4 + (tid >> 6);   // 0..383 = 12 ntiles x 32 ksteps
    const int lane = tid & 63;
    const int q    = lane >> 4, c = lane & 15;
    const int ntile = wid >> 5;
    const int kstep = wid & 31;
    const int n = ntile * 16 + c;                   // 0..191
    const int m = n >> 6;
    const float* W = (m == 0) ? Wq : (m == 1) ? Wk : Wv;
    const int ncol = n & 63;
    const int k0 = kstep * 32 + q * 8;
    u16x8 pk;
#pragma unroll
    for (int j = 0; j < 8; j++) pk[j] = f32_to_bf16(W[(size_t)(k0 + j) * H_ + ncol]);
    *(u16x8*)(Wt + (size_t)wid * 512 + lane * 8) = pk;
}

// ---- Kernel 1: QKV projection via bf16 MFMA --------------------------------
// 512 blocks x 256 thr. Block = 64 rows x 96 n (ng picks n-half of 192).
__global__ __launch_bounds__(256) void proj_kernel(
    const float* __restrict__ x, const unsigned short* __restrict__ Wt,
    unsigned short* __restrict__ Qb, unsigned short* __restrict__ Kb,
    unsigned short* __restrict__ Vb)
{
    __shared__ __align__(16) unsigned short xs[64][72];
    const int t    = threadIdx.x;
    const int rb   = blockIdx.x >> 1;
    const int ng   = blockIdx.x & 1;
    const int r0   = rb * 64;
    const int w    = t >> 6;
    const int lane = t & 63;
    const int quad = lane >> 4;
    const int c    = lane & 15;
    const int mh   = (w & 1) * 32;
    const int nh   = ng * 96 + (w >> 1) * 48;
    const int srow = t >> 2;        // 64 rows, 4 threads/row
    const int koff = (t & 3) * 16;  // 16 floats each

    f32x4 acc[2][3];
#pragma unroll
    for (int mi = 0; mi < 2; mi++)
#pragma unroll
        for (int j = 0; j < 3; j++) acc[mi][j] = {0.f, 0.f, 0.f, 0.f};

    const float* xp = x + (size_t)(r0 + srow) * C_ + koff;
    f32x4 v0 = *(const f32x4*)xp;
    f32x4 v1 = *(const f32x4*)(xp + 4);
    f32x4 v2 = *(const f32x4*)(xp + 8);
    f32x4 v3 = *(const f32x4*)(xp + 12);

    for (int kk = 0; kk < C_; kk += 64) {
        u16x8 p0, p1;
#pragma unroll
        for (int i = 0; i < 4; i++) {
            p0[i] = f32_to_bf16(v0[i]); p0[4 + i] = f32_to_bf16(v1[i]);
            p1[i] = f32_to_bf16(v2[i]); p1[4 + i] = f32_to_bf16(v3[i]);
        }
        __syncthreads();
        *(u16x8*)&xs[srow][koff]     = p0;
        *(u16x8*)&xs[srow][koff + 8] = p1;
        __syncthreads();
        if (kk + 64 < C_) {     // register prefetch of next x tile
            v0 = *(const f32x4*)(xp + kk + 64);
            v1 = *(const f32x4*)(xp + kk + 68);
            v2 = *(const f32x4*)(xp + kk + 72);
            v3 = *(const f32x4*)(xp + kk + 76);
        }
#pragma unroll
        for (int ks = 0; ks < 64; ks += 32) {
            const bf16x8 a0 = *(const bf16x8*)&xs[mh + c][ks + quad * 8];
            const bf16x8 a1 = *(const bf16x8*)&xs[mh + 16 + c][ks + quad * 8];
            const unsigned short* bp =
                Wt + ((size_t)(nh >> 4) * 32 + ((kk + ks) >> 5)) * 512 + lane * 8;
#pragma unroll
            for (int j = 0; j < 3; j++) {
                const bf16x8 bj = *(const bf16x8*)(bp + (size_t)j * 32 * 512);
                acc[0][j] = __builtin_amdgcn_mfma_f32_16x16x32_bf16(a0, bj, acc[0][j], 0, 0, 0);
                acc[1][j] = __builtin_amdgcn_mfma_f32_16x16x32_bf16(a1, bj, acc[1][j], 0, 0, 0);
            }
        }
    }

#pragma unroll
    for (int mi = 0; mi < 2; mi++) {
#pragma unroll
        for (int j = 0; j < 3; j++) {
            const int nt = nh + j * 16;      // 16-aligned -> wave-uniform select
            unsigned short* dst = (nt < 64) ? (Qb + nt)
                                : (nt < 128) ? (Kb + nt - 64)
                                             : (Vb + nt - 128);
#pragma unroll
            for (int r = 0; r < 4; r++) {
                const size_t row = (size_t)r0 + mh + mi * 16 + quad * 4 + r;
                dst[row * H_ + c] = f32_to_bf16(acc[mi][j][r]);
            }
        }
    }
}

// ---- Kernel 2: K,V -> fragment order (Kf, Vf) ------------------------------
// Kf[(b*256+kt)*1024 + half*512 + lane*8 + j] = A-frag K[kt*16+c][half*32+q*8+j]
// Vf[((b*128+k32)*4 + ht)*512 + lane*8 + j]   = A-frag V^T[ht*16+c][k32*32+q*8+j]
__global__ __launch_bounds__(256) void prep_kernel(
    const unsigned short* __restrict__ Kb, const unsigned short* __restrict__ Vb,
    unsigned short* __restrict__ Kf, unsigned short* __restrict__ Vf)
{
    __shared__ __align__(16) unsigned short vs[64][72];
    const int t    = threadIdx.x;
    const int r0   = blockIdx.x * 64;       // global row (64 | 4096: no b-cross)
    const int b    = r0 >> 12;
    const int kloc = r0 & 4095;
    const int w    = t >> 6, lane = t & 63, q = lane >> 4, c = lane & 15;

    // stage V tile: 64 rows x 64 cols; each thread stores 16 shorts (BUGFIX:
    // round-5 stored only 8 -> half the tile was uninitialized LDS)
    const int row = t >> 2, col = (t & 3) * 16;
    const unsigned short* vsrc = Vb + (size_t)(r0 + row) * H_ + col;
    u16x8 va0 = *(const u16x8*)vsrc;
    u16x8 va1 = *(const u16x8*)(vsrc + 8);
    *(u16x8*)&vs[row][col]     = va0;
    *(u16x8*)&vs[row][col + 8] = va1;

    // K reorder (register-only)
    const unsigned short* ksrc = Kb + (size_t)(r0 + w * 16 + c) * H_ + q * 8;
    u16x8 k0v = *(const u16x8*)ksrc;
    u16x8 k1v = *(const u16x8*)(ksrc + 32);
    const size_t kt = (size_t)b * 256 + (kloc >> 4) + w;
    *(u16x8*)(Kf + kt * 1024 + lane * 8)       = k0v;
    *(u16x8*)(Kf + kt * 1024 + 512 + lane * 8) = k1v;

    __syncthreads();
    // V frags: wave w = h-tile
#pragma unroll
    for (int kh = 0; kh < 2; kh++) {
        u16x8 pv;
#pragma unroll
        for (int j = 0; j < 8; j++) pv[j] = vs[kh * 32 + q * 8 + j][w * 16 + c];
        const size_t k32 = (size_t)b * 128 + (kloc >> 5) + kh;
        *(u16x8*)(Vf + (k32 * 4 + w) * 512 + lane * 8) = pv;
    }
}

// ---- Kernel 3: causal flash attention, transposed-S, uniform units ---------
// Unit = wave = (b, qt, ks): queries qt*16..+15, keys [ks*512, ks*512+512).
// S^T = K·Q^T -> softmax reduction is lane-local + 2 shfls; exp in base-2.
__global__ __launch_bounds__(256) void attn_kernel(
    const unsigned short* __restrict__ Qb, const unsigned short* __restrict__ Kf,
    const unsigned short* __restrict__ Vf, unsigned short* __restrict__ Opg,
    float* __restrict__ mlg)
{
    __shared__ __align__(16) unsigned short Pb[4][16][72];
    const int tid  = threadIdx.x;
    const int w    = tid >> 6;
    const int lane = tid & 63;
    const int quad = lane >> 4;
    const int c    = lane & 15;
    const int bid  = blockIdx.x;
    const int qt   = 255 - (bid >> 3);
    const int ks   = bid & 7;
    const int g    = qt >> 5;                 // nseg-1
    if (ks > g) return;
    const int b    = w;                       // wave = batch (equal work lengths)
    const int q0   = qt * 16;
    const int k0   = ks * 512;
    const int kend = (q0 + 15 < k0 + 511) ? q0 + 15 : k0 + 511;
    const size_t bT = (size_t)b * T_;

    const unsigned short* qp = Qb + (bT + q0 + c) * H_ + quad * 8;
    const bf16x8 qB0 = *(const bf16x8*)qp;
    const bf16x8 qB1 = *(const bf16x8*)(qp + 32);

    f32x4 O[4];
#pragma unroll
    for (int tt = 0; tt < 4; tt++) O[tt] = {0.f, 0.f, 0.f, 0.f};
    float m = -1e30f, ls = 0.f;
    const float scale2 = 0.045084436f;        // (1/32)*log2(e): exp -> exp2

    unsigned short* P = &Pb[w][0][0];
    const int prow = c * 72;

    for (int kb = k0; kb <= kend; kb += 64) {
        const unsigned short* kfb = Kf + ((size_t)b * 256 + (kb >> 4)) * 1024 + lane * 8;
        f32x4 S[4];
#pragma unroll
        for (int tt = 0; tt < 4; tt++) {
            const bf16x8 kA0 = *(const bf16x8*)(kfb + tt * 1024);
            const bf16x8 kA1 = *(const bf16x8*)(kfb + tt * 1024 + 512);
            f32x4 s = {0.f, 0.f, 0.f, 0.f};
            s = __builtin_amdgcn_mfma_f32_16x16x32_bf16(kA0, qB0, s, 0, 0, 0);
            s = __builtin_amdgcn_mfma_f32_16x16x32_bf16(kA1, qB1, s, 0, 0, 0);
            S[tt] = s;
        }
        float sc[16];
        if (kb + 63 > q0) {                   // diagonal chunk: causal mask
#pragma unroll
            for (int tt = 0; tt < 4; tt++)
#pragma unroll
                for (int r = 0; r < 4; r++) {
                    const int key = kb + tt * 16 + quad * 4 + r;
                    sc[tt * 4 + r] = (key > q0 + c) ? -1e30f : S[tt][r] * scale2;
                }
        } else {
#pragma unroll
            for (int tt = 0; tt < 4; tt++)
#pragma unroll
                for (int r = 0; r < 4; r++) sc[tt * 4 + r] = S[tt][r] * scale2;
        }
        float mx = sc[0];
#pragma unroll
        for (int i = 1; i < 16; i++) mx = fmaxf(mx, sc[i]);
        mx = fmaxf(mx, __shfl_xor(mx, 16));
        mx = fmaxf(mx, __shfl_xor(mx, 32));
        const float mn    = fmaxf(m, mx);
        const float alpha = exp2_hw(m - mn);
        m = mn;
        float lsum = 0.f;
#pragma unroll
        for (int tt = 0; tt < 4; tt++) {
            u16x4 pk;
#pragma unroll
            for (int r = 0; r < 4; r++) {
                const float e = exp2_hw(sc[tt * 4 + r] - mn);
                lsum += e;
                pk[r] = f32_to_bf16(e);
            }
            *(u16x4*)(P + prow + tt * 16 + quad * 4) = pk;   // P[query][key]
        }
        ls = ls * alpha + lsum;                // per-lane partial (this quad's keys)
#pragma unroll
        for (int tt = 0; tt < 4; tt++)
#pragma unroll
            for (int r = 0; r < 4; r++) O[tt][r] *= alpha;

        const bf16x8 pB0 = *(const bf16x8*)(P + prow + quad * 8);
        const bf16x8 pB1 = *(const bf16x8*)(P + prow + 32 + quad * 8);

        const unsigned short* vfb = Vf + ((size_t)b * 128 + (kb >> 5)) * 2048 + lane * 8;
#pragma unroll
        for (int tt = 0; tt < 4; tt++) {
            const bf16x8 vA0 = *(const bf16x8*)(vfb + tt * 512);
            const bf16x8 vA1 = *(const bf16x8*)(vfb + 2048 + tt * 512);
            O[tt] = __builtin_amdgcn_mfma_f32_16x16x32_bf16(vA0, pB0, O[tt], 0, 0, 0);
            O[tt] = __builtin_amdgcn_mfma_f32_16x16x32_bf16(vA1, pB1, O[tt], 0, 0, 0);
        }
    }

    ls += __shfl_xor(ls, 16);                 // total l for query c
    ls += __shfl_xor(ls, 32);

    const size_t ustore = (size_t)b * NUNIT_ + qt + 16 * g * (g - 1) + g * (qt & 31) + ks;
#pragma unroll
    for (int tt = 0; tt < 4; tt++) {
        u16x4 pk;
#pragma unroll
        for (int r = 0; r < 4; r++) pk[r] = f32_to_bf16(O[tt][r]);
        *(u16x4*)(Opg + ustore * 1024 + c * 64 + tt * 16 + quad * 4) = pk;
    }
    if (lane < 16) {
        mlg[ustore * 32 + c]      = m;        // log2-domain max
        mlg[ustore * 32 + 16 + c] = ls;
    }
}

// ---- Kernel 4: merge segments + normalize ----------------------------------
__global__ __launch_bounds__(256) void merge_kernel(
    const unsigned short* __restrict__ Opg, const float* __restrict__ mlg,
    float* __restrict__ out)
{
    const int idx = blockIdx.x;               // b*256 + qt
    const int b   = idx >> 8;
    const int qt  = idx & 255;
    const int g   = qt >> 5;
    const int nseg = g + 1;
    const size_t base = (size_t)b * NUNIT_ + qt + 16 * g * (g - 1) + g * (qt & 31);
    const int t  = threadIdx.x;
    const int h  = t & 63;
    const int rg = t >> 6;
#pragma unroll
    for (int i = 0; i < 4; i++) {
        const int row = rg * 4 + i;
        float M = -1e30f;
        for (int s = 0; s < nseg; s++) M = fmaxf(M, mlg[(base + s) * 32 + row]);
        float L = 0.f, val = 0.f;
        for (int s = 0; s < nseg; s++) {
            const float e = exp2_hw(mlg[(base + s) * 32 + row] - M);
            L   = fmaf(mlg[(base + s) * 32 + 16 + row], e, L);
            val = fmaf(bf16_to_f32(Opg[(base + s) * 1024 + row * 64 + h]), e, val);
        }
        out[((size_t)b * T_ + qt * 16 + row) * H_ + h] = val / L;
    }
}

extern "C" void kernel_launch(void* const* d_in, const int* in_sizes, int n_in,
                              void* d_out, int out_size, void* d_ws, size_t ws_size,
                              hipStream_t stream) {
    const float* x  = (const float*)d_in[0];
    const float* Wq = (const float*)d_in[1];
    const float* Wk = (const float*)d_in[2];
    const float* Wv = (const float*)d_in[3];
    float* out = (float*)d_out;

    // ws: Qb|Kb|Vb|Kf|Vf (2 MiB each) | Wt 384K | Opg 9.2 MiB | mlg 576K
    unsigned short* Qb = (unsigned short*)d_ws;
    unsigned short* Kb = Qb + (size_t)BT_ * H_;
    unsigned short* Vb = Kb + (size_t)BT_ * H_;
    unsigned short* Kf = Vb + (size_t)BT_ * H_;
    unsigned short* Vf = Kf + (size_t)BT_ * H_;
    unsigned short* Wt = Vf + (size_t)BT_ * H_;
    unsigned short* Opg = Wt + (size_t)192 * C_;
    float*          mlg = (float*)(Opg + (size_t)B_ * NUNIT_ * 1024);

    wconv_kernel<<<96, 256, 0, stream>>>(Wq, Wk, Wv, Wt);
    proj_kernel<<<512, 256, 0, stream>>>(x, Wt, Qb, Kb, Vb);
    prep_kernel<<<BT_ / 64, 256, 0, stream>>>(Kb, Vb, Kf, Vf);
    attn_kernel<<<2048, 256, 0, stream>>>(Qb, Kf, Vf, Opg, mlg);
    merge_kernel<<<1024, 256, 0, stream>>>(Opg, mlg, out);
}

// Round 8
// 171.886 us; speedup vs baseline: 2.0038x; 1.0617x over previous
//
#include <hip/hip_runtime.h>

constexpr int B_  = 4;
constexpr int T_  = 4096;
constexpr int C_  = 1024;
constexpr int H_  = 64;
constexpr int BT_ = B_ * T_;
constexpr int NUNIT_ = 1152;   // 512-key work units per batch: sum_qt (qt/32+1)

typedef __attribute__((ext_vector_type(4))) float f32x4;
typedef __attribute__((ext_vector_type(8))) short bf16x8;
typedef __attribute__((ext_vector_type(8))) unsigned short u16x8;
typedef __attribute__((ext_vector_type(4))) unsigned short u16x4;

__device__ __forceinline__ unsigned short f32_to_bf16(float f) {
    union { float f; unsigned int u; } v;
    v.f = f;
    unsigned int r = v.u + 0x7FFFu + ((v.u >> 16) & 1u);  // RNE
    return (unsigned short)(r >> 16);
}
__device__ __forceinline__ float bf16_to_f32(unsigned short us) {
    union { unsigned int u; float f; } v;
    v.u = (unsigned int)us << 16;
    return v.f;
}
// 2^x via v_exp_f32 (hardware transcendental); __exp2f does not exist in HIP.
__device__ __forceinline__ float exp2_hw(float x) {
    return __builtin_amdgcn_exp2f(x);
}

// ---- Kernel 0: W -> fragment-order Wt --------------------------------------
// Wt[(ntile*32 + kstep)*512 + lane*8 + j] = B-frag for MFMA(n-tile, 32k-step):
// lane(q,c): element j = W[n = ntile*16+c][k = kstep*32 + q*8 + j] (bf16).
__global__ __launch_bounds__(256) void wconv_kernel(
    const float* __restrict__ Wq, const float* __restrict__ Wk,
    const float* __restrict__ Wv, unsigned short* __restrict__ Wt)
{
    const int tid  = threadIdx.x;
    const int wid  = blockIdx.x * 4 + (tid >> 6);   // 0..383 = 12 ntiles x 32 ksteps
    const int lane = tid & 63;
    const int q    = lane >> 4, c = lane & 15;
    const int ntile = wid >> 5;
    const int kstep = wid & 31;
    const int n = ntile * 16 + c;                   // 0..191
    const int m = n >> 6;
    const float* W = (m == 0) ? Wq : (m == 1) ? Wk : Wv;
    const int ncol = n & 63;
    const int k0 = kstep * 32 + q * 8;
    u16x8 pk;
#pragma unroll
    for (int j = 0; j < 8; j++) pk[j] = f32_to_bf16(W[(size_t)(k0 + j) * H_ + ncol]);
    *(u16x8*)(Wt + (size_t)wid * 512 + lane * 8) = pk;
}

// ---- Kernel 1: QKV projection via bf16 MFMA --------------------------------
// 512 blocks x 256 thr. Block = 64 rows x 96 n (ng picks n-half of 192).
__global__ __launch_bounds__(256) void proj_kernel(
    const float* __restrict__ x, const unsigned short* __restrict__ Wt,
    unsigned short* __restrict__ Qb, unsigned short* __restrict__ Kb,
    unsigned short* __restrict__ Vb)
{
    __shared__ __align__(16) unsigned short xs[64][72];
    const int t    = threadIdx.x;
    const int rb   = blockIdx.x >> 1;
    const int ng   = blockIdx.x & 1;
    const int r0   = rb * 64;
    const int w    = t >> 6;
    const int lane = t & 63;
    const int quad = lane >> 4;
    const int c    = lane & 15;
    const int mh   = (w & 1) * 32;
    const int nh   = ng * 96 + (w >> 1) * 48;
    const int srow = t >> 2;        // 64 rows, 4 threads/row
    const int koff = (t & 3) * 16;  // 16 floats each

    f32x4 acc[2][3];
#pragma unroll
    for (int mi = 0; mi < 2; mi++)
#pragma unroll
        for (int j = 0; j < 3; j++) acc[mi][j] = {0.f, 0.f, 0.f, 0.f};

    const float* xp = x + (size_t)(r0 + srow) * C_ + koff;
    f32x4 v0 = *(const f32x4*)xp;
    f32x4 v1 = *(const f32x4*)(xp + 4);
    f32x4 v2 = *(const f32x4*)(xp + 8);
    f32x4 v3 = *(const f32x4*)(xp + 12);

    for (int kk = 0; kk < C_; kk += 64) {
        u16x8 p0, p1;
#pragma unroll
        for (int i = 0; i < 4; i++) {
            p0[i] = f32_to_bf16(v0[i]); p0[4 + i] = f32_to_bf16(v1[i]);
            p1[i] = f32_to_bf16(v2[i]); p1[4 + i] = f32_to_bf16(v3[i]);
        }
        __syncthreads();
        *(u16x8*)&xs[srow][koff]     = p0;
        *(u16x8*)&xs[srow][koff + 8] = p1;
        __syncthreads();
        if (kk + 64 < C_) {     // register prefetch of next x tile
            v0 = *(const f32x4*)(xp + kk + 64);
            v1 = *(const f32x4*)(xp + kk + 68);
            v2 = *(const f32x4*)(xp + kk + 72);
            v3 = *(const f32x4*)(xp + kk + 76);
        }
#pragma unroll
        for (int ks = 0; ks < 64; ks += 32) {
            const bf16x8 a0 = *(const bf16x8*)&xs[mh + c][ks + quad * 8];
            const bf16x8 a1 = *(const bf16x8*)&xs[mh + 16 + c][ks + quad * 8];
            const unsigned short* bp =
                Wt + ((size_t)(nh >> 4) * 32 + ((kk + ks) >> 5)) * 512 + lane * 8;
#pragma unroll
            for (int j = 0; j < 3; j++) {
                const bf16x8 bj = *(const bf16x8*)(bp + (size_t)j * 32 * 512);
                acc[0][j] = __builtin_amdgcn_mfma_f32_16x16x32_bf16(a0, bj, acc[0][j], 0, 0, 0);
                acc[1][j] = __builtin_amdgcn_mfma_f32_16x16x32_bf16(a1, bj, acc[1][j], 0, 0, 0);
            }
        }
    }

#pragma unroll
    for (int mi = 0; mi < 2; mi++) {
#pragma unroll
        for (int j = 0; j < 3; j++) {
            const int nt = nh + j * 16;      // 16-aligned -> wave-uniform select
            unsigned short* dst = (nt < 64) ? (Qb + nt)
                                : (nt < 128) ? (Kb + nt - 64)
                                             : (Vb + nt - 128);
#pragma unroll
            for (int r = 0; r < 4; r++) {
                const size_t row = (size_t)r0 + mh + mi * 16 + quad * 4 + r;
                dst[row * H_ + c] = f32_to_bf16(acc[mi][j][r]);
            }
        }
    }
}

// ---- Kernel 2: K,V -> fragment order (Kf, Vf) ------------------------------
// Kf[(b*256+kt)*1024 + half*512 + lane*8 + j] = A-frag K[kt*16+c][half*32+q*8+j]
// Vf[((b*128+k32)*4 + ht)*512 + lane*8 + j]   = A-frag V^T[ht*16+c][k32*32+q*8+j]
__global__ __launch_bounds__(256) void prep_kernel(
    const unsigned short* __restrict__ Kb, const unsigned short* __restrict__ Vb,
    unsigned short* __restrict__ Kf, unsigned short* __restrict__ Vf)
{
    __shared__ __align__(16) unsigned short vs[64][72];
    const int t    = threadIdx.x;
    const int r0   = blockIdx.x * 64;       // global row (64 | 4096: no b-cross)
    const int b    = r0 >> 12;
    const int kloc = r0 & 4095;
    const int w    = t >> 6, lane = t & 63, q = lane >> 4, c = lane & 15;

    // stage V tile: 64 rows x 64 cols; each thread stores 16 shorts
    const int row = t >> 2, col = (t & 3) * 16;
    const unsigned short* vsrc = Vb + (size_t)(r0 + row) * H_ + col;
    u16x8 va0 = *(const u16x8*)vsrc;
    u16x8 va1 = *(const u16x8*)(vsrc + 8);
    *(u16x8*)&vs[row][col]     = va0;
    *(u16x8*)&vs[row][col + 8] = va1;

    // K reorder (register-only)
    const unsigned short* ksrc = Kb + (size_t)(r0 + w * 16 + c) * H_ + q * 8;
    u16x8 k0v = *(const u16x8*)ksrc;
    u16x8 k1v = *(const u16x8*)(ksrc + 32);
    const size_t kt = (size_t)b * 256 + (kloc >> 4) + w;
    *(u16x8*)(Kf + kt * 1024 + lane * 8)       = k0v;
    *(u16x8*)(Kf + kt * 1024 + 512 + lane * 8) = k1v;

    __syncthreads();
    // V frags: wave w = h-tile
#pragma unroll
    for (int kh = 0; kh < 2; kh++) {
        u16x8 pv;
#pragma unroll
        for (int j = 0; j < 8; j++) pv[j] = vs[kh * 32 + q * 8 + j][w * 16 + c];
        const size_t k32 = (size_t)b * 128 + (kloc >> 5) + kh;
        *(u16x8*)(Vf + (k32 * 4 + w) * 512 + lane * 8) = pv;
    }
}

// ---- Kernel 3: causal flash attention, transposed-S, uniform units ---------
// Unit = wave = (b, qt, ks): queries qt*16..+15, keys [ks*512, ks*512+512).
// DECODE (round-8 fix): qt in LOW bits, ks in HIGH bits. Workgroup->XCD is
// round-robin on block index, so low bits must NOT correlate with ks: the old
// ks=bid&7 put all 256 ks=0 blocks on XCD0 (8 serial rounds; 13.6% occupancy).
__global__ __launch_bounds__(256) void attn_kernel(
    const unsigned short* __restrict__ Qb, const unsigned short* __restrict__ Kf,
    const unsigned short* __restrict__ Vf, unsigned short* __restrict__ Opg,
    float* __restrict__ mlg)
{
    __shared__ __align__(16) unsigned short Pb[4][16][72];
    const int tid  = threadIdx.x;
    const int w    = tid >> 6;
    const int lane = tid & 63;
    const int quad = lane >> 4;
    const int c    = lane & 15;
    const int bid  = blockIdx.x;
    const int qt   = 255 - (bid & 255);       // qt descending within ks-group
    const int ks   = bid >> 8;
    const int g    = qt >> 5;                 // nseg-1
    if (ks > g) return;
    const int b    = w;                       // wave = batch (equal work lengths)
    const int q0   = qt * 16;
    const int k0   = ks * 512;
    const int kend = (q0 + 15 < k0 + 511) ? q0 + 15 : k0 + 511;
    const size_t bT = (size_t)b * T_;

    const unsigned short* qp = Qb + (bT + q0 + c) * H_ + quad * 8;
    const bf16x8 qB0 = *(const bf16x8*)qp;
    const bf16x8 qB1 = *(const bf16x8*)(qp + 32);

    f32x4 O[4];
#pragma unroll
    for (int tt = 0; tt < 4; tt++) O[tt] = {0.f, 0.f, 0.f, 0.f};
    float m = -1e30f, ls = 0.f;
    const float scale2 = 0.045084436f;        // (1/32)*log2(e): exp -> exp2

    unsigned short* P = &Pb[w][0][0];
    const int prow = c * 72;

    for (int kb = k0; kb <= kend; kb += 64) {
        const unsigned short* kfb = Kf + ((size_t)b * 256 + (kb >> 4)) * 1024 + lane * 8;
        f32x4 S[4];
#pragma unroll
        for (int tt = 0; tt < 4; tt++) {
            const bf16x8 kA0 = *(const bf16x8*)(kfb + tt * 1024);
            const bf16x8 kA1 = *(const bf16x8*)(kfb + tt * 1024 + 512);
            f32x4 s = {0.f, 0.f, 0.f, 0.f};
            s = __builtin_amdgcn_mfma_f32_16x16x32_bf16(kA0, qB0, s, 0, 0, 0);
            s = __builtin_amdgcn_mfma_f32_16x16x32_bf16(kA1, qB1, s, 0, 0, 0);
            S[tt] = s;
        }
        float sc[16];
        if (kb + 63 > q0) {                   // diagonal chunk: causal mask
#pragma unroll
            for (int tt = 0; tt < 4; tt++)
#pragma unroll
                for (int r = 0; r < 4; r++) {
                    const int key = kb + tt * 16 + quad * 4 + r;
                    sc[tt * 4 + r] = (key > q0 + c) ? -1e30f : S[tt][r] * scale2;
                }
        } else {
#pragma unroll
            for (int tt = 0; tt < 4; tt++)
#pragma unroll
                for (int r = 0; r < 4; r++) sc[tt * 4 + r] = S[tt][r] * scale2;
        }
        float mx = sc[0];
#pragma unroll
        for (int i = 1; i < 16; i++) mx = fmaxf(mx, sc[i]);
        mx = fmaxf(mx, __shfl_xor(mx, 16));
        mx = fmaxf(mx, __shfl_xor(mx, 32));
        const float mn    = fmaxf(m, mx);
        const float alpha = exp2_hw(m - mn);
        m = mn;
        float lsum = 0.f;
#pragma unroll
        for (int tt = 0; tt < 4; tt++) {
            u16x4 pk;
#pragma unroll
            for (int r = 0; r < 4; r++) {
                const float e = exp2_hw(sc[tt * 4 + r] - mn);
                lsum += e;
                pk[r] = f32_to_bf16(e);
            }
            *(u16x4*)(P + prow + tt * 16 + quad * 4) = pk;   // P[query][key]
        }
        ls = ls * alpha + lsum;                // per-lane partial (this quad's keys)
#pragma unroll
        for (int tt = 0; tt < 4; tt++)
#pragma unroll
            for (int r = 0; r < 4; r++) O[tt][r] *= alpha;

        const bf16x8 pB0 = *(const bf16x8*)(P + prow + quad * 8);
        const bf16x8 pB1 = *(const bf16x8*)(P + prow + 32 + quad * 8);

        const unsigned short* vfb = Vf + ((size_t)b * 128 + (kb >> 5)) * 2048 + lane * 8;
#pragma unroll
        for (int tt = 0; tt < 4; tt++) {
            const bf16x8 vA0 = *(const bf16x8*)(vfb + tt * 512);
            const bf16x8 vA1 = *(const bf16x8*)(vfb + 2048 + tt * 512);
            O[tt] = __builtin_amdgcn_mfma_f32_16x16x32_bf16(vA0, pB0, O[tt], 0, 0, 0);
            O[tt] = __builtin_amdgcn_mfma_f32_16x16x32_bf16(vA1, pB1, O[tt], 0, 0, 0);
        }
    }

    ls += __shfl_xor(ls, 16);                 // total l for query c
    ls += __shfl_xor(ls, 32);

    const size_t ustore = (size_t)b * NUNIT_ + qt + 16 * g * (g - 1) + g * (qt & 31) + ks;
#pragma unroll
    for (int tt = 0; tt < 4; tt++) {
        u16x4 pk;
#pragma unroll
        for (int r = 0; r < 4; r++) pk[r] = f32_to_bf16(O[tt][r]);
        *(u16x4*)(Opg + ustore * 1024 + c * 64 + tt * 16 + quad * 4) = pk;
    }
    if (lane < 16) {
        mlg[ustore * 32 + c]      = m;        // log2-domain max
        mlg[ustore * 32 + 16 + c] = ls;
    }
}

// ---- Kernel 4: merge segments + normalize ----------------------------------
__global__ __launch_bounds__(256) void merge_kernel(
    const unsigned short* __restrict__ Opg, const float* __restrict__ mlg,
    float* __restrict__ out)
{
    const int idx = blockIdx.x;               // b*256 + qt
    const int b   = idx >> 8;
    const int qt  = idx & 255;
    const int g   = qt >> 5;
    const int nseg = g + 1;
    const size_t base = (size_t)b * NUNIT_ + qt + 16 * g * (g - 1) + g * (qt & 31);
    const int t  = threadIdx.x;
    const int h  = t & 63;
    const int rg = t >> 6;
#pragma unroll
    for (int i = 0; i < 4; i++) {
        const int row = rg * 4 + i;
        float M = -1e30f;
        for (int s = 0; s < nseg; s++) M = fmaxf(M, mlg[(base + s) * 32 + row]);
        float L = 0.f, val = 0.f;
        for (int s = 0; s < nseg; s++) {
            const float e = exp2_hw(mlg[(base + s) * 32 + row] - M);
            L   = fmaf(mlg[(base + s) * 32 + 16 + row], e, L);
            val = fmaf(bf16_to_f32(Opg[(base + s) * 1024 + row * 64 + h]), e, val);
        }
        out[((size_t)b * T_ + qt * 16 + row) * H_ + h] = val / L;
    }
}

extern "C" void kernel_launch(void* const* d_in, const int* in_sizes, int n_in,
                              void* d_out, int out_size, void* d_ws, size_t ws_size,
                              hipStream_t stream) {
    const float* x  = (const float*)d_in[0];
    const float* Wq = (const float*)d_in[1];
    const float* Wk = (const float*)d_in[2];
    const float* Wv = (const float*)d_in[3];
    float* out = (float*)d_out;

    // ws: Qb|Kb|Vb|Kf|Vf (2 MiB each) | Wt 384K | Opg 9.2 MiB | mlg 576K
    unsigned short* Qb = (unsigned short*)d_ws;
    unsigned short* Kb = Qb + (size_t)BT_ * H_;
    unsigned short* Vb = Kb + (size_t)BT_ * H_;
    unsigned short* Kf = Vb + (size_t)BT_ * H_;
    unsigned short* Vf = Kf + (size_t)BT_ * H_;
    unsigned short* Wt = Vf + (size_t)BT_ * H_;
    unsigned short* Opg = Wt + (size_t)192 * C_;
    float*          mlg = (float*)(Opg + (size_t)B_ * NUNIT_ * 1024);

    wconv_kernel<<<96, 256, 0, stream>>>(Wq, Wk, Wv, Wt);
    proj_kernel<<<512, 256, 0, stream>>>(x, Wt, Qb, Kb, Vb);
    prep_kernel<<<BT_ / 64, 256, 0, stream>>>(Kb, Vb, Kf, Vf);
    attn_kernel<<<2048, 256, 0, stream>>>(Qb, Kf, Vf, Opg, mlg);
    merge_kernel<<<1024, 256, 0, stream>>>(Opg, mlg, out);
}